// Round 7
// baseline (182.470 us; speedup 1.0000x reference)
//
#include <hip/hip_runtime.h>
#include <hip/hip_bf16.h>

// ---- problem constants ----
#define HID   1024
#define NEXP  8
#define NPAIR 4096                       // TOKENS * TOPK
#define PERM_MAX (NPAIR + NEXP * 128)    // 5120

typedef unsigned short u16;
typedef __attribute__((ext_vector_type(8))) short bf16x8;
typedef __attribute__((ext_vector_type(4))) float f32x4;
typedef __attribute__((ext_vector_type(4))) unsigned short us4;

static __device__ __forceinline__ u16 f2bf(float f) {
  union { float f; unsigned u; } v; v.f = f;
  unsigned u = v.u;
  unsigned r = (u + 0x7fffu + ((u >> 16) & 1u)) >> 16;
  return (u16)r;
}

// pack 2 f32 -> 2 bf16 (v_cvt_pk_bf16_f32)
static __device__ __forceinline__ unsigned pk2(float a, float b) {
  __hip_bfloat162 h = __float22bfloat162_rn(make_float2(a, b));
  union { __hip_bfloat162 h; unsigned u; } c; c.h = h; return c.u;
}

// 8 f32 -> bf16x8 fragment
static __device__ __forceinline__ bf16x8 cvt8(f32x4 a, f32x4 b) {
  union { unsigned u[4]; bf16x8 v; } r;
  r.u[0] = pk2(a[0], a[1]); r.u[1] = pk2(a[2], a[3]);
  r.u[2] = pk2(b[0], b[1]); r.u[3] = pk2(b[2], b[3]);
  return r.v;
}

static __device__ __forceinline__ void gload16(const void* g, void* l) {
  __builtin_amdgcn_global_load_lds(
      (const __attribute__((address_space(1))) unsigned int*)g,
      (__attribute__((address_space(3))) unsigned int*)l, 16, 0, 0);
}

static __device__ __forceinline__ f32x4 mfma_bf16(bf16x8 a, bf16x8 b, f32x4 c) {
  return __builtin_amdgcn_mfma_f32_16x16x32_bf16(a, b, c, 0, 0, 0);
}

// ---- prep: zero d_out, convert x -> bf16 ----
__global__ __launch_bounds__(256) void k_prep(const float* __restrict__ x,
                                              u16* __restrict__ xb,
                                              float* __restrict__ out) {
  int i = blockIdx.x * 256 + threadIdx.x;
  int base = i * 8;
  f32x4 v0 = *(const f32x4*)(x + base);
  f32x4 v1 = *(const f32x4*)(x + base + 4);
  us4 a = { f2bf(v0[0]), f2bf(v0[1]), f2bf(v0[2]), f2bf(v0[3]) };
  us4 b = { f2bf(v1[0]), f2bf(v1[1]), f2bf(v1[2]), f2bf(v1[3]) };
  *(us4*)(xb + base)     = a;
  *(us4*)(xb + base + 4) = b;
  f32x4 z = {0.f, 0.f, 0.f, 0.f};
  *(f32x4*)(out + base)     = z;
  *(f32x4*)(out + base + 4) = z;
}

// ---- routing: counts -> 128-padded segment bases -> permutation ----
__global__ __launch_bounds__(256) void k_route(const int* __restrict__ sel,
                                               int* __restrict__ hdr,
                                               int* __restrict__ perm) {
  __shared__ int cnt[NEXP];
  __shared__ int cur[NEXP];
  int tid = threadIdx.x;
  if (tid < NEXP) cnt[tid] = 0;
  __syncthreads();
  for (int p = tid; p < NPAIR; p += 256) atomicAdd(&cnt[sel[p]], 1);
  __syncthreads();
  if (tid == 0) {
    int acc = 0;
    for (int e = 0; e < NEXP; e++) {
      hdr[e] = acc;
      cur[e] = acc;
      acc += (cnt[e] + 127) & ~127;
    }
    hdr[NEXP] = acc;
  }
  __syncthreads();
  for (int i = tid; i < PERM_MAX; i += 256) perm[i] = -1;
  __syncthreads();
  for (int p = tid; p < NPAIR; p += 256) {
    int e = sel[p];
    int slot = atomicAdd(&cur[e], 1);
    perm[slot] = p;
  }
}

// ==== GEMM 1: gate+up fused, weights-in-registers, read-once ====
// Block = (expert e, 32-col slice nt). 4 waves: (mat = wv>>1 in {gate,up},
// cg = wv&1 selects 16 cols). Each wave holds its 16 weight rows x full K=1024
// in 32 bf16x8 register fragments (converted f32->bf16 on load, read ONCE).
// mt-loop over the expert's 128-row chunks; A staged via global_load_lds into a
// tri-buffered LDS pipeline with counted vmcnt + raw barriers (never drains in-loop).
__global__ __launch_bounds__(256, 1) void k_gateup(const u16* __restrict__ xb,
                                                   const float* __restrict__ gw,
                                                   const float* __restrict__ uw,
                                                   const int* __restrict__ hdr,
                                                   const int* __restrict__ perm,
                                                   u16* __restrict__ hbuf) {
  __shared__ __align__(16) u16 lA[3][128 * 64];    // 48 KB tri-buffer
  __shared__ __align__(16) float lG[2][8 * 256];   // 16 KB: g-acc transfer per cg

  const int tid = threadIdx.x, lane = tid & 63, wv = tid >> 6;
  const int e = blockIdx.x & 7, nt = blockIdx.x >> 3;   // e -> XCD pin; nt 0..31
  const int seg0 = hdr[e], seg1 = hdr[e + 1];
  const int mcnt = (seg1 - seg0) >> 7;
  if (mcnt == 0) return;
  const int fr = lane & 15, fq = lane >> 4;
  const int mat = wv >> 1, cg = wv & 1;

  // ---- B load phase: 16 rows x K=1024, f32 -> 32 bf16x8 frags (128 VGPR) ----
  const float* bw = (mat == 0 ? gw : uw) + ((size_t)e << 20)
                    + (size_t)(nt * 32 + cg * 16 + fr) * HID + fq * 8;
  bf16x8 bfrag[32];
  #pragma unroll
  for (int s = 0; s < 32; s++) {
    f32x4 lo = *(const f32x4*)(bw + s * 32);
    f32x4 hi = *(const f32x4*)(bw + s * 32 + 4);
    bfrag[s] = cvt8(lo, hi);
  }

  f32x4 acc[8];
  for (int mt = 0; mt < mcnt; mt++) {
    const int m0 = seg0 + mt * 128;
    // A staging map: chunk c = tid + 256j -> row r=c>>3, 16B slot q=c&7,
    // LDS linear dest, global source pre-swizzled (q ^ (r&7)).
    const u16* srcA[4]; int dstAo[4];
    #pragma unroll
    for (int j = 0; j < 4; j++) {
      int c = tid + 256 * j;
      int r = c >> 3, q = c & 7;
      int p = perm[m0 + r];
      int tok = (p < 0) ? 0 : (p >> 1);
      srcA[j] = xb + (size_t)tok * HID + (q ^ (r & 7)) * 8;
      dstAo[j] = r * 64 + q * 8;
    }
    #pragma unroll
    for (int i = 0; i < 8; i++) acc[i] = (f32x4){0.f, 0.f, 0.f, 0.f};

    // drain prior-mt stores / B-phase remnants; sync lA[0] & lG reuse
    asm volatile("s_waitcnt vmcnt(0)\ns_barrier" ::: "memory");
    __builtin_amdgcn_sched_barrier(0);

    #pragma unroll
    for (int j = 0; j < 4; j++) gload16(srcA[j], &lA[0][dstAo[j]]);
    #pragma unroll
    for (int t = 0; t < 16; t++) {
      if (t < 15) {
        #pragma unroll
        for (int j = 0; j < 4; j++)
          gload16(srcA[j] + (t + 1) * 64, &lA[(t + 1) % 3][dstAo[j]]);
        asm volatile("s_waitcnt vmcnt(4)\ns_barrier" ::: "memory");
      } else {
        asm volatile("s_waitcnt vmcnt(0)\ns_barrier" ::: "memory");
      }
      __builtin_amdgcn_sched_barrier(0);
      const u16* la = lA[t % 3];
      #pragma unroll
      for (int kk2 = 0; kk2 < 2; kk2++) {
        #pragma unroll
        for (int m2 = 0; m2 < 8; m2++) {
          int r = m2 * 16 + fr, q = kk2 * 4 + fq;
          bf16x8 af = *(const bf16x8*)&la[r * 64 + (q ^ (r & 7)) * 8];
          acc[m2] = mfma_bf16(af, bfrag[t * 2 + kk2], acc[m2]);
        }
      }
    }

    // epilogue: gate waves publish g via LDS; up waves compute h = silu(g)*u
    if (mat == 0) {
      #pragma unroll
      for (int m2 = 0; m2 < 8; m2++)
        #pragma unroll
        for (int q = 0; q < 4; q++)
          lG[cg][m2 * 256 + (fq * 4 + q) * 16 + fr] = acc[m2][q];
    }
    asm volatile("s_waitcnt lgkmcnt(0)\ns_barrier" ::: "memory");
    if (mat == 1) {
      #pragma unroll
      for (int m2 = 0; m2 < 8; m2++)
        #pragma unroll
        for (int q = 0; q < 4; q++) {
          float g = lG[cg][m2 * 256 + (fq * 4 + q) * 16 + fr];
          float u = acc[m2][q];
          float h = (g / (1.0f + __expf(-g))) * u;
          int row = m0 + m2 * 16 + fq * 4 + q;
          hbuf[(size_t)row * HID + nt * 32 + cg * 16 + fr] = f2bf(h);
        }
    }
  }
}

// ==== GEMM 2: down, weights-in-registers, read-once, atomic scatter ====
// Block = (e, 32-col slice). 2 waves, each owns 16 out-cols x full K=1024 in regs.
__global__ __launch_bounds__(128, 1) void k_down(const u16* __restrict__ hbuf,
                                                 const float* __restrict__ dw,
                                                 const int* __restrict__ hdr,
                                                 const int* __restrict__ perm,
                                                 const float* __restrict__ rw,
                                                 float* __restrict__ out) {
  __shared__ __align__(16) u16 lA[3][128 * 64];   // 48 KB tri-buffer

  const int tid = threadIdx.x, lane = tid & 63, wv = tid >> 6;  // wv 0..1
  const int e = blockIdx.x & 7, nt = blockIdx.x >> 3;           // nt 0..31
  const int seg0 = hdr[e], seg1 = hdr[e + 1];
  const int mcnt = (seg1 - seg0) >> 7;
  if (mcnt == 0) return;
  const int fr = lane & 15, fq = lane >> 4;
  const int col = nt * 32 + wv * 16 + fr;

  const float* bw = dw + ((size_t)e << 20) + (size_t)col * HID + fq * 8;
  bf16x8 bfrag[32];
  #pragma unroll
  for (int s = 0; s < 32; s++) {
    f32x4 lo = *(const f32x4*)(bw + s * 32);
    f32x4 hi = *(const f32x4*)(bw + s * 32 + 4);
    bfrag[s] = cvt8(lo, hi);
  }

  f32x4 acc[8];
  for (int mt = 0; mt < mcnt; mt++) {
    const int m0 = seg0 + mt * 128;
    const u16* srcA[8]; int dstAo[8];
    #pragma unroll
    for (int j = 0; j < 8; j++) {
      int c = tid + 128 * j;
      int r = c >> 3, q = c & 7;
      srcA[j] = hbuf + (size_t)(m0 + r) * HID + (q ^ (r & 7)) * 8;
      dstAo[j] = r * 64 + q * 8;
    }
    #pragma unroll
    for (int i = 0; i < 8; i++) acc[i] = (f32x4){0.f, 0.f, 0.f, 0.f};

    asm volatile("s_waitcnt vmcnt(0)\ns_barrier" ::: "memory");
    __builtin_amdgcn_sched_barrier(0);

    #pragma unroll
    for (int j = 0; j < 8; j++) gload16(srcA[j], &lA[0][dstAo[j]]);
    #pragma unroll
    for (int t = 0; t < 16; t++) {
      if (t < 15) {
        #pragma unroll
        for (int j = 0; j < 8; j++)
          gload16(srcA[j] + (t + 1) * 64, &lA[(t + 1) % 3][dstAo[j]]);
        asm volatile("s_waitcnt vmcnt(8)\ns_barrier" ::: "memory");
      } else {
        asm volatile("s_waitcnt vmcnt(0)\ns_barrier" ::: "memory");
      }
      __builtin_amdgcn_sched_barrier(0);
      const u16* la = lA[t % 3];
      #pragma unroll
      for (int kk2 = 0; kk2 < 2; kk2++) {
        #pragma unroll
        for (int m2 = 0; m2 < 8; m2++) {
          int r = m2 * 16 + fr, q = kk2 * 4 + fq;
          bf16x8 af = *(const bf16x8*)&la[r * 64 + (q ^ (r & 7)) * 8];
          acc[m2] = mfma_bf16(af, bfrag[t * 2 + kk2], acc[m2]);
        }
      }
    }

    // epilogue: out[token, col] += w * val
    #pragma unroll
    for (int m2 = 0; m2 < 8; m2++)
      #pragma unroll
      for (int q = 0; q < 4; q++) {
        int row = m0 + m2 * 16 + fq * 4 + q;
        int p = perm[row];
        if (p >= 0) {
          atomicAdd(&out[(size_t)(p >> 1) * HID + col], acc[m2][q] * rw[p]);
        }
      }
  }
}

extern "C" void kernel_launch(void* const* d_in, const int* in_sizes, int n_in,
                              void* d_out, int out_size, void* d_ws, size_t ws_size,
                              hipStream_t stream) {
  const float* x   = (const float*)d_in[0];
  const float* rw  = (const float*)d_in[1];
  const int*   sel = (const int*)d_in[2];
  const float* gw  = (const float*)d_in[4];
  const float* uw  = (const float*)d_in[5];
  const float* dw  = (const float*)d_in[6];
  float* out = (float*)d_out;

  char* ws = (char*)d_ws;
  int*  hdr  = (int*)ws;                          // seg_base[9]
  int*  perm = (int*)(ws + 1024);                 // PERM_MAX ints
  u16*  xb   = (u16*)(ws + (1 << 16));            // 2M bf16 = 4 MiB
  u16*  hbuf = xb + (2 << 20);                    // 5120*1024 bf16 = 10 MiB

  k_prep <<<dim3(1024), dim3(256), 0, stream>>>(x, xb, out);
  k_route<<<dim3(1),    dim3(256), 0, stream>>>(sel, hdr, perm);
  k_gateup<<<dim3(256), dim3(256), 0, stream>>>(xb, gw, uw, hdr, perm, hbuf);
  k_down  <<<dim3(256), dim3(128), 0, stream>>>(hbuf, dw, hdr, perm, rw, out);
}

// Round 8
// 126.108 us; speedup vs baseline: 1.4469x; 1.4469x over previous
//
#include <hip/hip_runtime.h>
#include <hip/hip_bf16.h>

// ---- problem constants ----
#define HID   1024
#define NEXP  8
#define NPAIR 4096                       // TOKENS * TOPK
#define PERM_MAX (NPAIR + NEXP * 128)    // 5120
#define MT_CAP 16                        // mt slots per (e, nt); stride loop covers overflow

typedef unsigned short u16;
typedef __attribute__((ext_vector_type(8))) short bf16x8;
typedef __attribute__((ext_vector_type(4))) float f32x4;
typedef __attribute__((ext_vector_type(4))) unsigned short us4;

static __device__ __forceinline__ u16 f2bf(float f) {
  union { float f; unsigned u; } v; v.f = f;
  unsigned u = v.u;
  unsigned r = (u + 0x7fffu + ((u >> 16) & 1u)) >> 16;
  return (u16)r;
}

static __device__ __forceinline__ void gload16(const void* g, void* l) {
  __builtin_amdgcn_global_load_lds(
      (const __attribute__((address_space(1))) unsigned int*)g,
      (__attribute__((address_space(3))) unsigned int*)l, 16, 0, 0);
}

static __device__ __forceinline__ f32x4 mfma_bf16(bf16x8 a, bf16x8 b, f32x4 c) {
  return __builtin_amdgcn_mfma_f32_16x16x32_bf16(a, b, c, 0, 0, 0);
}

static __device__ __forceinline__ void conv8(const float* src, u16* dst) {
  f32x4 v0 = *(const f32x4*)src;
  f32x4 v1 = *(const f32x4*)(src + 4);
  us4 a = { f2bf(v0[0]), f2bf(v0[1]), f2bf(v0[2]), f2bf(v0[3]) };
  us4 b = { f2bf(v1[0]), f2bf(v1[1]), f2bf(v1[2]), f2bf(v1[3]) };
  *(us4*)dst       = a;
  *(us4*)(dst + 4) = b;
}

// ---- prep: zero d_out, convert x + gate_w + up_w -> bf16 (one streaming pass) ----
__global__ __launch_bounds__(256) void k_prep(const float* __restrict__ x,
                                              const float* __restrict__ gw,
                                              const float* __restrict__ uw,
                                              u16* __restrict__ xb,
                                              u16* __restrict__ gwb,
                                              u16* __restrict__ uwb,
                                              float* __restrict__ out) {
  const int i = blockIdx.x * 256 + threadIdx.x;   // 1024 blocks -> 262144 threads
  // x (2M elems) + out zero (2M elems)
  {
    int base = i * 8;
    conv8(x + base, xb + base);
    f32x4 z = {0.f, 0.f, 0.f, 0.f};
    *(f32x4*)(out + base)     = z;
    *(f32x4*)(out + base + 4) = z;
  }
  // gw, uw: 8M elems each = 1M chunks-of-8; 4 chunks per thread
  #pragma unroll
  for (int j = 0; j < 4; j++) {
    long c = (long)i + 262144L * j;
    long off = c * 8;
    conv8(gw + off, gwb + off);
    conv8(uw + off, uwb + off);
  }
}

// ---- routing: counts -> 128-padded segment bases -> permutation ----
__global__ __launch_bounds__(256) void k_route(const int* __restrict__ sel,
                                               int* __restrict__ hdr,
                                               int* __restrict__ perm) {
  __shared__ int cnt[NEXP];
  __shared__ int cur[NEXP];
  int tid = threadIdx.x;
  if (tid < NEXP) cnt[tid] = 0;
  __syncthreads();
  for (int p = tid; p < NPAIR; p += 256) atomicAdd(&cnt[sel[p]], 1);
  __syncthreads();
  if (tid == 0) {
    int acc = 0;
    for (int e = 0; e < NEXP; e++) {
      hdr[e] = acc;
      cur[e] = acc;
      acc += (cnt[e] + 127) & ~127;
    }
    hdr[NEXP] = acc;
  }
  __syncthreads();
  for (int i = tid; i < PERM_MAX; i += 256) perm[i] = -1;
  __syncthreads();
  for (int p = tid; p < NPAIR; p += 256) {
    int e = sel[p];
    int slot = atomicAdd(&cur[e], 1);
    perm[slot] = p;
  }
}

// ==== GEMM 1: gate+up fused, SwiGLU -> hbuf (bf16) ====
// BM=128, BN=32 per matrix, BK=64; 4 waves 2x2 (per wave 64 rows x 16 cols per matrix).
// Single-buffered LDS, R2-proven schedule. Expert pinned to XCD via e = bid&7;
// mt-inner block order so same-(e,nt) blocks (sharing the B tile) co-reside.
// Tail: each block converts its slice of down_w f32->bf16 (overlaps other blocks' GEMM).
__global__ __launch_bounds__(256) void k_gateup(const u16* __restrict__ xb,
                                                const u16* __restrict__ gwb,
                                                const u16* __restrict__ uwb,
                                                const float* __restrict__ dw,
                                                u16* __restrict__ dwb,
                                                const int* __restrict__ hdr,
                                                const int* __restrict__ perm,
                                                u16* __restrict__ hbuf) {
  __shared__ __align__(16) u16 lA[128 * 64];   // 16 KB
  __shared__ __align__(16) u16 lBg[32 * 64];   //  4 KB
  __shared__ __align__(16) u16 lBu[32 * 64];   //  4 KB   (24 KB -> 6 blocks/CU)

  const int tid = threadIdx.x, lane = tid & 63, wv = tid >> 6;
  const int bid = blockIdx.x;
  const int e = bid & 7;                 // XCD pin
  const int idx = bid >> 3;              // 0..511
  const int nt = idx >> 4;               // 0..31 (32-col slice)
  const int mt0 = idx & 15;              // mt slot
  const int seg0 = hdr[e];
  const int mcnt = (hdr[e + 1] - seg0) >> 7;
  const int n0 = nt * 32;

  const int wm = wv >> 1, wn = wv & 1;
  const int fr = lane & 15, fq = lane >> 4;
  const size_t eb = (size_t)e << 20;

  // B staging: 256 chunks of 16B per matrix; 1 per thread. LDS linear, src pre-swizzled.
  const int br = tid >> 3, bq = tid & 7;
  const u16* srcG = gwb + eb + (size_t)(n0 + br) * HID + (bq ^ (br & 7)) * 8;
  const u16* srcU = uwb + eb + (size_t)(n0 + br) * HID + (bq ^ (br & 7)) * 8;
  const int dstBo = br * 64 + bq * 8;

  for (int mt = mt0; mt < mcnt; mt += MT_CAP) {
    const int m0 = seg0 + mt * 128;
    const u16* srcA[4]; int dstAo[4];
    #pragma unroll
    for (int j = 0; j < 4; j++) {
      int c = tid + 256 * j;
      int r = c >> 3, q = c & 7;
      int p = perm[m0 + r];
      int tok = (p < 0) ? 0 : (p >> 1);
      srcA[j] = xb + (size_t)tok * HID + (q ^ (r & 7)) * 8;
      dstAo[j] = r * 64 + q * 8;
    }

    f32x4 accg[4], accu[4];
    #pragma unroll
    for (int a = 0; a < 4; a++) {
      accg[a] = (f32x4){0.f, 0.f, 0.f, 0.f};
      accu[a] = (f32x4){0.f, 0.f, 0.f, 0.f};
    }

    for (int kk = 0; kk < 16; kk++) {
      const int k0 = kk * 64;
      #pragma unroll
      for (int j = 0; j < 4; j++) gload16(srcA[j] + k0, &lA[dstAo[j]]);
      gload16(srcG + k0, &lBg[dstBo]);
      gload16(srcU + k0, &lBu[dstBo]);
      __syncthreads();
      #pragma unroll
      for (int kk2 = 0; kk2 < 2; kk2++) {
        bf16x8 af[4], bg, bu;
        #pragma unroll
        for (int m2 = 0; m2 < 4; m2++) {
          int r = wm * 64 + m2 * 16 + fr, q = kk2 * 4 + fq;
          af[m2] = *(const bf16x8*)&lA[r * 64 + (q ^ (r & 7)) * 8];
        }
        {
          int r = wn * 16 + fr, q = kk2 * 4 + fq;
          bg = *(const bf16x8*)&lBg[r * 64 + (q ^ (r & 7)) * 8];
          bu = *(const bf16x8*)&lBu[r * 64 + (q ^ (r & 7)) * 8];
        }
        #pragma unroll
        for (int m2 = 0; m2 < 4; m2++) {
          accg[m2] = mfma_bf16(af[m2], bg, accg[m2]);
          accu[m2] = mfma_bf16(af[m2], bu, accu[m2]);
        }
      }
      __syncthreads();
    }

    // epilogue: h = silu(g) * u -> bf16
    #pragma unroll
    for (int m2 = 0; m2 < 4; m2++)
      #pragma unroll
      for (int q = 0; q < 4; q++) {
        int row = m0 + wm * 64 + m2 * 16 + fq * 4 + q;
        int col = n0 + wn * 16 + fr;
        float g = accg[m2][q];
        float u = accu[m2][q];
        float h = (g / (1.0f + __expf(-g))) * u;
        hbuf[(size_t)row * HID + col] = f2bf(h);
      }
  }

  // ---- tail: convert this block's slice of down_w (expert e) f32 -> bf16 ----
  // per expert: 1M elems = 131072 chunks-of-8; 512 blocks/expert x 256 threads = exact cover.
  {
    long off = ((long)e << 20) + ((long)(idx * 256 + tid)) * 8;
    conv8(dw + off, dwb + off);
  }
}

// ==== GEMM 2: down, weighted atomic scatter into out ====
// BM=128, BN=64, BK=64; 4 waves 2x2; R2-proven schedule; expert pinned via e = bid&7.
__global__ __launch_bounds__(256) void k_down(const u16* __restrict__ hbuf,
                                              const u16* __restrict__ dwb,
                                              const int* __restrict__ hdr,
                                              const int* __restrict__ perm,
                                              const float* __restrict__ rw,
                                              float* __restrict__ out) {
  __shared__ __align__(16) u16 lA[128 * 64];   // 16 KB
  __shared__ __align__(16) u16 lB[64 * 64];    //  8 KB   (24 KB -> 6 blocks/CU)

  const int tid = threadIdx.x, lane = tid & 63, wv = tid >> 6;
  const int bid = blockIdx.x;
  const int e = bid & 7;
  const int idx = bid >> 3;              // 0..255
  const int nt = idx >> 4;               // 0..15 (64-col slice)
  const int mt0 = idx & 15;
  const int seg0 = hdr[e];
  const int mcnt = (hdr[e + 1] - seg0) >> 7;
  const int n0 = nt * 64;

  const int wm = wv >> 1, wn = wv & 1;
  const int fr = lane & 15, fq = lane >> 4;
  const size_t eb = (size_t)e << 20;

  // B staging: 512 chunks of 16B; 2 per thread.
  const u16* srcB[2]; int dstBo[2];
  #pragma unroll
  for (int j = 0; j < 2; j++) {
    int c = tid + 256 * j;
    int r = c >> 3, q = c & 7;
    srcB[j] = dwb + eb + (size_t)(n0 + r) * HID + (q ^ (r & 7)) * 8;
    dstBo[j] = r * 64 + q * 8;
  }

  for (int mt = mt0; mt < mcnt; mt += MT_CAP) {
    const int m0 = seg0 + mt * 128;
    const u16* srcA[4]; int dstAo[4];
    #pragma unroll
    for (int j = 0; j < 4; j++) {
      int c = tid + 256 * j;
      int r = c >> 3, q = c & 7;
      srcA[j] = hbuf + (size_t)(m0 + r) * HID + (q ^ (r & 7)) * 8;
      dstAo[j] = r * 64 + q * 8;
    }

    f32x4 acc[4][2];
    #pragma unroll
    for (int a = 0; a < 4; a++)
      #pragma unroll
      for (int b = 0; b < 2; b++) acc[a][b] = (f32x4){0.f, 0.f, 0.f, 0.f};

    for (int kk = 0; kk < 16; kk++) {
      const int k0 = kk * 64;
      #pragma unroll
      for (int j = 0; j < 4; j++) gload16(srcA[j] + k0, &lA[dstAo[j]]);
      #pragma unroll
      for (int j = 0; j < 2; j++) gload16(srcB[j] + k0, &lB[dstBo[j]]);
      __syncthreads();
      #pragma unroll
      for (int kk2 = 0; kk2 < 2; kk2++) {
        bf16x8 af[4], bf[2];
        #pragma unroll
        for (int m2 = 0; m2 < 4; m2++) {
          int r = wm * 64 + m2 * 16 + fr, q = kk2 * 4 + fq;
          af[m2] = *(const bf16x8*)&lA[r * 64 + (q ^ (r & 7)) * 8];
        }
        #pragma unroll
        for (int n2 = 0; n2 < 2; n2++) {
          int r = wn * 32 + n2 * 16 + fr, q = kk2 * 4 + fq;
          bf[n2] = *(const bf16x8*)&lB[r * 64 + (q ^ (r & 7)) * 8];
        }
        #pragma unroll
        for (int m2 = 0; m2 < 4; m2++)
          #pragma unroll
          for (int n2 = 0; n2 < 2; n2++)
            acc[m2][n2] = mfma_bf16(af[m2], bf[n2], acc[m2][n2]);
      }
      __syncthreads();
    }

    // epilogue: out[token] += w * val
    #pragma unroll
    for (int m2 = 0; m2 < 4; m2++)
      #pragma unroll
      for (int q = 0; q < 4; q++) {
        int row = m0 + wm * 64 + m2 * 16 + fq * 4 + q;
        int p = perm[row];
        if (p < 0) continue;
        int t = p >> 1;
        float w = rw[p];
        #pragma unroll
        for (int n2 = 0; n2 < 2; n2++) {
          int col = n0 + wn * 32 + n2 * 16 + fr;
          atomicAdd(&out[(size_t)t * HID + col], acc[m2][n2][q] * w);
        }
      }
  }
}

extern "C" void kernel_launch(void* const* d_in, const int* in_sizes, int n_in,
                              void* d_out, int out_size, void* d_ws, size_t ws_size,
                              hipStream_t stream) {
  const float* x   = (const float*)d_in[0];
  const float* rw  = (const float*)d_in[1];
  const int*   sel = (const int*)d_in[2];
  const float* gw  = (const float*)d_in[4];
  const float* uw  = (const float*)d_in[5];
  const float* dw  = (const float*)d_in[6];
  float* out = (float*)d_out;

  char* ws = (char*)d_ws;
  int*  hdr  = (int*)ws;                          // seg_base[9]
  int*  perm = (int*)(ws + 1024);                 // PERM_MAX ints
  u16*  xb   = (u16*)(ws + (1 << 16));            // 2M bf16  =  4 MiB
  u16*  gwb  = xb + (2 << 20);                    // 8M bf16  = 16 MiB
  u16*  uwb  = gwb + (8 << 20);                   // 16 MiB
  u16*  dwb  = uwb + (8 << 20);                   // 16 MiB
  u16*  hbuf = dwb + (8 << 20);                   // 10 MiB

  k_prep  <<<dim3(1024), dim3(256), 0, stream>>>(x, gw, uw, xb, gwb, uwb, out);
  k_route <<<dim3(1),    dim3(256), 0, stream>>>(sel, hdr, perm);
  k_gateup<<<dim3(8 * 32 * MT_CAP), dim3(256), 0, stream>>>(xb, gwb, uwb, dw, dwb, hdr, perm, hbuf);
  k_down  <<<dim3(8 * 16 * MT_CAP), dim3(256), 0, stream>>>(hbuf, dwb, hdr, perm, rw, out);
}